// Round 1
// baseline (2855.949 us; speedup 1.0000x reference)
//
#include <hip/hip_runtime.h>
#include <math.h>

#define CC 192
#define TTT 768
#define PP 29
#define LOG2PI_F 1.8378770664093453f

__device__ __forceinline__ float geluf(float x){
  // jax.nn.gelu approximate=True: 0.5x(1+tanh(sqrt(2/pi)(x+0.044715x^3))) == x*sigmoid(2*sqrt(2/pi)*(x+0.044715x^3))
  float u = 1.5957691216057308f * (x + 0.044715f*x*x*x);
  return x * __builtin_amdgcn_rcpf(1.f + __expf(-u));
}
__device__ __forceinline__ float softplus_f(float x){
  return (x > 20.f) ? x : log1pf(__expf(x));
}
__device__ __forceinline__ float logsig_f(float x){
  return -softplus_f(-x);
}

// ---------------- conv 192x192 over a 32-wide t tile, epilogue modes ----------------
// mode 0: out = acc + bias
// mode 1: out = (acc + bias) * mask
// mode 2: out = (acc + bias) * mask + addsrc
__global__ __launch_bounds__(192) void conv_cc_k(
    const float* __restrict__ in, const float* __restrict__ W,
    const float* __restrict__ bias, const float* __restrict__ mask,
    const float* __restrict__ addsrc, float* __restrict__ out, int mode){
  __shared__ float smem[CC*36];   // phase1: [ci][t] stride 36 ; phase2 alias: [t][co] stride 193
  int b = blockIdx.y, t0 = blockIdx.x*32;
  int tid = threadIdx.x;
  int tl = tid & 31, cs = tid >> 5;           // 6 csets x 32 ci
  const float* inb = in + ((size_t)b*CC)*TTT + t0;
  for (int j=0;j<32;j++){
    int ci = cs*32 + j;
    smem[ci*36 + tl] = inb[(size_t)ci*TTT + tl];
  }
  __syncthreads();
  float acc[32];
  #pragma unroll
  for (int i=0;i<32;i++) acc[i]=0.f;
  const float* Wr = W + (size_t)tid*CC;
  float4 w4 = *(const float4*)Wr;
  for (int ci=0; ci<CC; ci+=4){
    float4 wn = make_float4(0.f,0.f,0.f,0.f);
    if (ci+4 < CC) wn = *(const float4*)(Wr+ci+4);
    float wa[4] = {w4.x,w4.y,w4.z,w4.w};
    #pragma unroll
    for (int u=0;u<4;u++){
      const float* xr = &smem[(ci+u)*36];
      #pragma unroll
      for (int q=0;q<8;q++){
        float4 xv = *(const float4*)(xr + q*4);
        acc[q*4+0] = fmaf(wa[u], xv.x, acc[q*4+0]);
        acc[q*4+1] = fmaf(wa[u], xv.y, acc[q*4+1]);
        acc[q*4+2] = fmaf(wa[u], xv.z, acc[q*4+2]);
        acc[q*4+3] = fmaf(wa[u], xv.w, acc[q*4+3]);
      }
    }
    w4 = wn;
  }
  __syncthreads();
  #pragma unroll
  for (int t=0;t<32;t++) smem[t*193 + tid] = acc[t];
  __syncthreads();
  float* outb = out + ((size_t)b*CC)*TTT + t0;
  float mv = mask[(size_t)b*TTT + t0 + tl];
  for (int j=0;j<32;j++){
    int c2 = cs*32 + j;
    float v = smem[tl*193 + c2] + bias[c2];
    if (mode >= 1) v *= mv;
    if (mode == 2) v += addsrc[((size_t)b*CC + c2)*TTT + t0 + tl];
    outb[(size_t)c2*TTT + tl] = v;
  }
}

// ---------------- one DDS layer: depthwise(x*mask)+b -> LN -> gelu -> conv1x1+b -> LN -> gelu -> +x ----------------
__global__ __launch_bounds__(192) void dds_layer_k(
    const float* __restrict__ in, float* __restrict__ out,
    const float* __restrict__ mask,
    const float* __restrict__ dw, const float* __restrict__ db,
    const float* __restrict__ g0, const float* __restrict__ b0,
    const float* __restrict__ pw, const float* __restrict__ pb,
    const float* __restrict__ g1, const float* __restrict__ b1,
    int dil){
  __shared__ float bufA[32*193];
  __shared__ float bufB[CC*36];
  __shared__ float mst[32], rst[32];
  int b = blockIdx.y, t0 = blockIdx.x*32;
  int tid = threadIdx.x;
  int tl = tid & 31, cs = tid >> 5;
  int tg = t0 + tl;
  const float* inb = in + ((size_t)b*CC)*TTT;
  const float* mk = mask + (size_t)b*TTT;
  float mc  = mk[tg];
  float mlv = (tg-dil >= 0)  ? mk[tg-dil] : 0.f;
  float mrv = (tg+dil < TTT) ? mk[tg+dil] : 0.f;
  // P1: depthwise
  for (int j=0;j<32;j++){
    int c = cs*32 + j;
    const float* xr = inb + (size_t)c*TTT;
    float xl = (tg-dil >= 0)  ? xr[tg-dil]*mlv : 0.f;
    float xc = xr[tg]*mc;
    float xv = (tg+dil < TTT) ? xr[tg+dil]*mrv : 0.f;
    bufA[tl*193 + c] = fmaf(dw[c*3], xl, fmaf(dw[c*3+1], xc, fmaf(dw[c*3+2], xv, db[c])));
  }
  __syncthreads();
  // P2: LN stats over channels per t
  if (tid < 32){
    float s=0.f,q=0.f;
    for (int c=0;c<CC;c++){ float v=bufA[tid*193+c]; s+=v; q=fmaf(v,v,q); }
    float m = s*(1.f/CC);
    float var = q*(1.f/CC) - m*m;
    mst[tid]=m; rst[tid]=rsqrtf(var + 1e-5f);
  }
  __syncthreads();
  // P3: normalize + gelu -> bufB[ci][t]
  for (int j=0;j<32;j++){
    int c = cs*32 + j;
    float v = (bufA[tl*193+c]-mst[tl])*rst[tl]*g0[c] + b0[c];
    bufB[c*36 + tl] = geluf(v);
  }
  __syncthreads();
  // P4: conv 192x192
  float acc[32];
  #pragma unroll
  for (int i=0;i<32;i++) acc[i]=0.f;
  const float* Wr = pw + (size_t)tid*CC;
  float4 w4 = *(const float4*)Wr;
  for (int ci=0; ci<CC; ci+=4){
    float4 wn = make_float4(0.f,0.f,0.f,0.f);
    if (ci+4 < CC) wn = *(const float4*)(Wr+ci+4);
    float wa[4] = {w4.x,w4.y,w4.z,w4.w};
    #pragma unroll
    for (int u=0;u<4;u++){
      const float* xr = &bufB[(ci+u)*36];
      #pragma unroll
      for (int q=0;q<8;q++){
        float4 xv = *(const float4*)(xr + q*4);
        acc[q*4+0] = fmaf(wa[u], xv.x, acc[q*4+0]);
        acc[q*4+1] = fmaf(wa[u], xv.y, acc[q*4+1]);
        acc[q*4+2] = fmaf(wa[u], xv.z, acc[q*4+2]);
        acc[q*4+3] = fmaf(wa[u], xv.w, acc[q*4+3]);
      }
    }
    w4 = wn;
  }
  float bb = pb[tid];
  #pragma unroll
  for (int t=0;t<32;t++) bufA[t*193 + tid] = acc[t] + bb;
  __syncthreads();
  // P5: LN stats again
  if (tid < 32){
    float s=0.f,q=0.f;
    for (int c=0;c<CC;c++){ float v=bufA[tid*193+c]; s+=v; q=fmaf(v,v,q); }
    float m = s*(1.f/CC);
    float var = q*(1.f/CC) - m*m;
    mst[tid]=m; rst[tid]=rsqrtf(var + 1e-5f);
  }
  __syncthreads();
  // P6: normalize + gelu + residual
  for (int j=0;j<32;j++){
    int c = cs*32 + j;
    float v = (bufA[tl*193+c]-mst[tl])*rst[tl]*g1[c] + b1[c];
    out[((size_t)b*CC + c)*TTT + tg] = inb[(size_t)c*TTT + tg] + geluf(v);
  }
}

// ---------------- rank-1 pre-conv: out[b,c,t] = pw[c]*src[b,t] + pb[c] (+ g[b,c,t]) ----------------
__global__ __launch_bounds__(256) void bcast_pre_k(
    const float* __restrict__ src, int sstride,
    const float* __restrict__ pwv, const float* __restrict__ pbv,
    const float* __restrict__ g, float* __restrict__ out){
  int b = blockIdx.y, t0 = blockIdx.x*64;
  int tid = threadIdx.x; int tl = tid & 63, cs = tid >> 6;  // 4 csets x 48 c
  float x0 = src[(size_t)b*sstride + t0 + tl];
  for (int j=0;j<48;j++){
    int c = cs*48 + j;
    float v = fmaf(pwv[c], x0, pbv[c]);
    if (g) v += g[((size_t)b*CC + c)*TTT + t0 + tl];
    out[((size_t)b*CC + c)*TTT + t0 + tl] = v;
  }
}

// ---------------- 29x192 projection, *mask ----------------
__global__ __launch_bounds__(256) void proj29_k(
    const float* __restrict__ in, const float* __restrict__ W,
    const float* __restrict__ bias, const float* __restrict__ mask,
    float* __restrict__ outp){
  __shared__ float xt[CC*64];
  int b = blockIdx.y, t0 = blockIdx.x*64;
  int tid = threadIdx.x; int tl = tid & 63, cs = tid >> 6;
  for (int j=0;j<48;j++){
    int ci = cs*48 + j;
    xt[ci*64 + tl] = in[((size_t)b*CC + ci)*TTT + t0 + tl];
  }
  __syncthreads();
  int co = tid & 31, tg8 = tid >> 5;   // 8 t-groups of 8
  if (co < PP){
    float acc[8];
    #pragma unroll
    for (int i=0;i<8;i++) acc[i]=bias[co];
    const float* Wr = W + (size_t)co*CC;
    for (int ci=0; ci<CC; ci+=4){
      float4 w4 = *(const float4*)(Wr+ci);
      float wa[4]={w4.x,w4.y,w4.z,w4.w};
      #pragma unroll
      for (int u=0;u<4;u++){
        const float* xr = &xt[(ci+u)*64 + tg8*8];
        float4 a  = *(const float4*)xr;
        float4 c4 = *(const float4*)(xr+4);
        acc[0]=fmaf(wa[u],a.x,acc[0]);  acc[1]=fmaf(wa[u],a.y,acc[1]);
        acc[2]=fmaf(wa[u],a.z,acc[2]);  acc[3]=fmaf(wa[u],a.w,acc[3]);
        acc[4]=fmaf(wa[u],c4.x,acc[4]); acc[5]=fmaf(wa[u],c4.y,acc[5]);
        acc[6]=fmaf(wa[u],c4.z,acc[6]); acc[7]=fmaf(wa[u],c4.w,acc[7]);
      }
    }
    #pragma unroll
    for (int k=0;k<8;k++){
      int t = tg8*8 + k;
      outp[((size_t)b*PP + co)*TTT + t0 + t] = acc[k]*mask[(size_t)b*TTT + t0 + t];
    }
  }
}

// ---------------- RQS spline coupling; updates z planes, acc[b] -= sum(lad*m) ----------------
__global__ __launch_bounds__(256) void spline_k(
    float* __restrict__ z, int s, const float* __restrict__ proj,
    const float* __restrict__ mask, float* __restrict__ acc){
  __shared__ float red[256];
  int b = blockIdx.y; int t = blockIdx.x*256 + threadIdx.x;
  const float scv = 0.07216878364870323f;   // 1/sqrt(192)
  float m = mask[(size_t)b*TTT + t];
  float* z0p = z + ((size_t)b*2 + s)*TTT + t;
  float* z1p = z + ((size_t)b*2 + (1-s))*TTT + t;
  float xs = *z1p;
  const float* hp = proj + (size_t)b*PP*TTT + t;
  float uw[10], uh[10], ud[9];
  #pragma unroll
  for (int k=0;k<10;k++) uw[k]=hp[(size_t)k*TTT]*scv;
  #pragma unroll
  for (int k=0;k<10;k++) uh[k]=hp[(size_t)(10+k)*TTT]*scv;
  #pragma unroll
  for (int k=0;k<9;k++)  ud[k]=hp[(size_t)(20+k)*TTT];
  bool inside = (xs >= -5.f) && (xs <= 5.f);
  float xc = fminf(fmaxf(xs,-5.f),5.f);
  // widths softmax
  float mx=uw[0];
  #pragma unroll
  for (int k=1;k<10;k++) mx=fmaxf(mx,uw[k]);
  float sw=0.f; float wd[10];
  #pragma unroll
  for (int k=0;k<10;k++){ wd[k]=__expf(uw[k]-mx); sw+=wd[k]; }
  float invw = 1.f/sw;
  #pragma unroll
  for (int k=0;k<10;k++) wd[k]=fmaf(0.99f*invw, wd[k], 1e-3f);
  // heights softmax
  float mh=uh[0];
  #pragma unroll
  for (int k=1;k<10;k++) mh=fmaxf(mh,uh[k]);
  float sh=0.f; float ht[10];
  #pragma unroll
  for (int k=0;k<10;k++){ ht[k]=__expf(uh[k]-mh); sh+=ht[k]; }
  float invh = 1.f/sh;
  #pragma unroll
  for (int k=0;k<10;k++) ht[k]=fmaf(0.99f*invh, ht[k], 1e-3f);
  // width bin scan: idx = last i with cw_i <= xc
  float cw=-5.f, icw=-5.f, iw=1.f; int idx=0;
  #pragma unroll
  for (int i=0;i<10;i++){
    float nw = (i==9) ? 5.f : fmaf(10.f, wd[i], cw);
    if (cw <= xc){ idx=i; icw=cw; iw=nw-cw; }
    cw=nw;
  }
  // height cumsum gather at idx
  float ch=-5.f, ich=-5.f, ih=1.f;
  #pragma unroll
  for (int i=0;i<10;i++){
    float nh = (i==9) ? 5.f : fmaf(10.f, ht[i], ch);
    if (i==idx){ ich=ch; ih=nh-ch; }
    ch=nh;
  }
  // derivatives (ud padded both ends with log(expm1(0.999)))
  const float UDC = logf(expm1f(0.999f));
  float d0=1.f, d1=1.f;
  #pragma unroll
  for (int k=0;k<11;k++){
    float uu = (k==0 || k==10) ? UDC : ud[k-1];
    float dk = 1e-3f + softplus_f(uu);
    if (k==idx)   d0=dk;
    if (k==idx+1) d1=dk;
  }
  float idel = ih/iw;
  float th = (xc-icw)/iw;
  float t1m = th*(1.f-th);
  float den = idel + (d0+d1-2.f*idel)*t1m;
  float outv = ich + ih*(idel*th*th + d0*t1m)/den;
  float omt = 1.f-th;
  float dnum = idel*idel*(d1*th*th + 2.f*idel*t1m + d0*omt*omt);
  float lad = logf(dnum) - 2.f*logf(den);
  float y = inside ? outv : xs;
  lad = inside ? lad : 0.f;
  *z1p = y*m;
  *z0p = (*z0p)*m;
  int tid = threadIdx.x;
  red[tid] = lad*m;
  __syncthreads();
  for (int o=128;o>0;o>>=1){ if (tid<o) red[tid]+=red[tid+o]; __syncthreads(); }
  if (tid==0) atomicAdd(acc+b, -red[0]);
}

// ---------------- z init from e_q + paff affine; acc += e-terms and -paff ld ----------------
__global__ __launch_bounds__(256) void init_z_k(
    const float* __restrict__ e_q, const float* __restrict__ mask,
    const float* __restrict__ pm, const float* __restrict__ pl,
    float* __restrict__ z, float* __restrict__ acc){
  __shared__ float red[256];
  int b = blockIdx.y; int t = blockIdx.x*256 + threadIdx.x;
  float m = mask[(size_t)b*TTT + t];
  float pl0=pl[0], pl1=pl[1];
  float e0 = e_q[((size_t)b*2+0)*TTT + t]*m;
  float e1 = e_q[((size_t)b*2+1)*TTT + t]*m;
  z[((size_t)b*2+0)*TTT + t] = fmaf(__expf(pl0), e0, pm[0])*m;
  z[((size_t)b*2+1)*TTT + t] = fmaf(__expf(pl1), e1, pm[1])*m;
  float contrib = -0.5f*(LOG2PI_F + e0*e0)*m - 0.5f*(LOG2PI_F + e1*e1)*m - (pl0+pl1)*m;
  int tid = threadIdx.x;
  red[tid] = contrib;
  __syncthreads();
  for (int o=128;o>0;o>>=1){ if (tid<o) red[tid]+=red[tid+o]; __syncthreads(); }
  if (tid==0) atomicAdd(acc+b, red[0]);
}

// ---------------- between p-flows and f-flows ----------------
__global__ __launch_bounds__(256) void final_pre_k(
    float* __restrict__ z, const float* __restrict__ w_in, const float* __restrict__ mask,
    const float* __restrict__ am, const float* __restrict__ al, float* __restrict__ acc){
  __shared__ float red[256];
  int b = blockIdx.y; int t = blockIdx.x*256 + threadIdx.x;
  float m = mask[(size_t)b*TTT + t];
  float zu  = z[((size_t)b*2+0)*TTT + t];
  float z1v = z[((size_t)b*2+1)*TTT + t];
  float wv  = w_in[(size_t)b*TTT + t];
  float u  = m / (1.f + __expf(-zu));       // sigmoid(zu)*m
  float z0 = (wv - u)*m;
  float y0 = logf(fmaxf(z0, 1e-5f))*m;
  float al0=al[0], al1=al[1];
  z[((size_t)b*2+0)*TTT + t] = fmaf(__expf(al0), y0,  am[0])*m;
  z[((size_t)b*2+1)*TTT + t] = fmaf(__expf(al1), z1v, am[1])*m;
  float contrib = -(logsig_f(zu)+logsig_f(-zu))*m + y0 - (al0+al1)*m;
  int tid = threadIdx.x;
  red[tid] = contrib;
  __syncthreads();
  for (int o=128;o>0;o>>=1){ if (tid<o) red[tid]+=red[tid+o]; __syncthreads(); }
  if (tid==0) atomicAdd(acc+b, red[0]);
}

// ---------------- final 0.5(log2pi + z^2) sum ----------------
__global__ __launch_bounds__(256) void final_post_k(
    const float* __restrict__ z, const float* __restrict__ mask, float* __restrict__ acc){
  __shared__ float red[256];
  int b = blockIdx.y; int t = blockIdx.x*256 + threadIdx.x;
  float m = mask[(size_t)b*TTT + t];
  float z0 = z[((size_t)b*2+0)*TTT + t];
  float z1 = z[((size_t)b*2+1)*TTT + t];
  float contrib = 0.5f*(LOG2PI_F + z0*z0)*m + 0.5f*(LOG2PI_F + z1*z1)*m;
  int tid = threadIdx.x;
  red[tid] = contrib;
  __syncthreads();
  for (int o=128;o>0;o>>=1){ if (tid<o) red[tid]+=red[tid+o]; __syncthreads(); }
  if (tid==0) atomicAdd(acc+b, red[0]);
}

__global__ void write_out_k(const float* __restrict__ acc, float* __restrict__ out, int n){
  int i = threadIdx.x;
  if (i < n) out[i] = acc[i];
}

extern "C" void kernel_launch(void* const* d_in, const int* in_sizes, int n_in,
                              void* d_out, int out_size, void* d_ws, size_t ws_size,
                              hipStream_t stream){
  (void)n_in; (void)out_size; (void)ws_size;
  const float* x         = (const float*)d_in[0];
  const float* mask      = (const float*)d_in[1];
  const float* w_in      = (const float*)d_in[2];
  const float* e_q       = (const float*)d_in[3];
  const float* pre_w     = (const float*)d_in[4];
  const float* pre_b     = (const float*)d_in[5];
  const float* proj_w    = (const float*)d_in[6];
  const float* proj_b    = (const float*)d_in[7];
  const float* dds_dep_w = (const float*)d_in[8];
  const float* dds_dep_b = (const float*)d_in[9];
  const float* dds_pw_w  = (const float*)d_in[10];
  const float* dds_pw_b  = (const float*)d_in[11];
  const float* dds_ln_g  = (const float*)d_in[12];
  const float* dds_ln_b  = (const float*)d_in[13];
  const float* post_pre_w  = (const float*)d_in[14];
  const float* post_pre_b  = (const float*)d_in[15];
  const float* post_proj_w = (const float*)d_in[16];
  const float* post_proj_b = (const float*)d_in[17];
  const float* pdds_dep_w  = (const float*)d_in[18];
  const float* pdds_dep_b  = (const float*)d_in[19];
  const float* pdds_pw_w   = (const float*)d_in[20];
  const float* pdds_pw_b   = (const float*)d_in[21];
  const float* pdds_ln_g   = (const float*)d_in[22];
  const float* pdds_ln_b   = (const float*)d_in[23];
  const float* aff_m    = (const float*)d_in[24];
  const float* aff_logs = (const float*)d_in[25];
  const float* f_pre_w  = (const float*)d_in[26];
  const float* f_pre_b  = (const float*)d_in[27];
  const float* f_dep_w  = (const float*)d_in[28];
  const float* f_dep_b  = (const float*)d_in[29];
  const float* f_pw_w   = (const float*)d_in[30];
  const float* f_pw_b   = (const float*)d_in[31];
  const float* f_ln_g   = (const float*)d_in[32];
  const float* f_ln_b   = (const float*)d_in[33];
  const float* f_proj_w = (const float*)d_in[34];
  const float* f_proj_b = (const float*)d_in[35];
  const float* paff_m    = (const float*)d_in[36];
  const float* paff_logs = (const float*)d_in[37];
  const float* p_pre_w  = (const float*)d_in[38];
  const float* p_pre_b  = (const float*)d_in[39];
  const float* p_dep_w  = (const float*)d_in[40];
  const float* p_dep_b  = (const float*)d_in[41];
  const float* p_pw_w   = (const float*)d_in[42];
  const float* p_pw_b   = (const float*)d_in[43];
  const float* p_ln_g   = (const float*)d_in[44];
  const float* p_ln_b   = (const float*)d_in[45];
  const float* p_proj_w = (const float*)d_in[46];
  const float* p_proj_b = (const float*)d_in[47];

  int Bn = in_sizes[0] / (CC*TTT);
  size_t big = (size_t)Bn*CC*TTT;
  float* A    = (float*)d_ws;
  float* Bb   = A + big;
  float* H    = Bb + big;
  float* GP   = H + big;
  float* pbuf = GP + big;
  float* zbuf = pbuf + (size_t)Bn*PP*TTT;
  float* acc  = zbuf + (size_t)Bn*2*TTT;

  hipMemsetAsync(acc, 0, Bn*sizeof(float), stream);

  dim3 g32(TTT/32, Bn), g64(TTT/64, Bn), g256(TTT/256, Bn);
  dim3 b192(192), b256(256);

  auto dds3 = [&](const float* dep_w, const float* dep_b, const float* pw_w,
                  const float* pw_b, const float* ln_g, const float* ln_b,
                  float* bin, float* bout){
    const int dils[3] = {1,3,9};
    const float* src[3] = {bin, bout, bin};
    float* dst[3]       = {bout, bin, bout};
    for (int i=0;i<3;i++){
      dds_layer_k<<<g32, b192, 0, stream>>>(src[i], dst[i], mask,
        dep_w + (size_t)i*CC*3, dep_b + (size_t)i*CC,
        ln_g + (size_t)(i*2+0)*CC, ln_b + (size_t)(i*2+0)*CC,
        pw_w + (size_t)i*CC*CC, pw_b + (size_t)i*CC,
        ln_g + (size_t)(i*2+1)*CC, ln_b + (size_t)(i*2+1)*CC, dils[i]);
    }
  };

  // ---- h path ----
  conv_cc_k<<<g32, b192, 0, stream>>>(x, pre_w, pre_b, mask, nullptr, A, 0);
  dds3(dds_dep_w, dds_dep_b, dds_pw_w, dds_pw_b, dds_ln_g, dds_ln_b, A, Bb);
  conv_cc_k<<<g32, b192, 0, stream>>>(Bb, proj_w, proj_b, mask, nullptr, H, 1);

  // ---- hw path ----
  bcast_pre_k<<<g64, b256, 0, stream>>>(w_in, TTT, post_pre_w, post_pre_b, nullptr, A);
  dds3(pdds_dep_w, pdds_dep_b, pdds_pw_w, pdds_pw_b, pdds_ln_g, pdds_ln_b, A, Bb);
  conv_cc_k<<<g32, b192, 0, stream>>>(Bb, post_proj_w, post_proj_b, mask, H, GP, 2);

  // ---- init z from e_q ----
  init_z_k<<<g256, b256, 0, stream>>>(e_q, mask, paff_m, paff_logs, zbuf, acc);

  // ---- 4 posterior flows (g = GP) ----
  for (int f=0; f<4; f++){
    int s = f & 1;
    bcast_pre_k<<<g64, b256, 0, stream>>>(zbuf + (size_t)s*TTT, 2*TTT,
        p_pre_w + (size_t)f*CC, p_pre_b + (size_t)f*CC, GP, A);
    dds3(p_dep_w + (size_t)f*3*CC*3, p_dep_b + (size_t)f*3*CC,
         p_pw_w + (size_t)f*3*CC*CC, p_pw_b + (size_t)f*3*CC,
         p_ln_g + (size_t)f*3*2*CC, p_ln_b + (size_t)f*3*2*CC, A, Bb);
    proj29_k<<<g64, b256, 0, stream>>>(Bb, p_proj_w + (size_t)f*PP*CC,
        p_proj_b + (size_t)f*PP, mask, pbuf);
    spline_k<<<g256, b256, 0, stream>>>(zbuf, s, pbuf, mask, acc);
  }

  // ---- transition: sigmoid/log terms + aff affine ----
  final_pre_k<<<g256, b256, 0, stream>>>(zbuf, w_in, mask, aff_m, aff_logs, acc);

  // ---- 4 flows (g = H) ----
  for (int f=0; f<4; f++){
    int s = f & 1;
    bcast_pre_k<<<g64, b256, 0, stream>>>(zbuf + (size_t)s*TTT, 2*TTT,
        f_pre_w + (size_t)f*CC, f_pre_b + (size_t)f*CC, H, A);
    dds3(f_dep_w + (size_t)f*3*CC*3, f_dep_b + (size_t)f*3*CC,
         f_pw_w + (size_t)f*3*CC*CC, f_pw_b + (size_t)f*3*CC,
         f_ln_g + (size_t)f*3*2*CC, f_ln_b + (size_t)f*3*2*CC, A, Bb);
    proj29_k<<<g64, b256, 0, stream>>>(Bb, f_proj_w + (size_t)f*PP*CC,
        f_proj_b + (size_t)f*PP, mask, pbuf);
    spline_k<<<g256, b256, 0, stream>>>(zbuf, s, pbuf, mask, acc);
  }

  final_post_k<<<g256, b256, 0, stream>>>(zbuf, mask, acc);
  write_out_k<<<1, 64, 0, stream>>>(acc, (float*)d_out, Bn);
}

// Round 2
// 2556.853 us; speedup vs baseline: 1.1170x; 1.1170x over previous
//
#include <hip/hip_runtime.h>
#include <math.h>

#define CC 192
#define TTT 768
#define PP 29
#define LOG2PI_F 1.8378770664093453f
#define WSLOT 36864   // 192*192

typedef __attribute__((ext_vector_type(8))) short short8;
typedef __attribute__((ext_vector_type(4))) float floatx4;
union Frag { int4 i; short8 s; };

__device__ __forceinline__ float geluf(float x){
  float u = 1.5957691216057308f * (x + 0.044715f*x*x*x);
  return x * __builtin_amdgcn_rcpf(1.f + __expf(-u));
}
__device__ __forceinline__ float softplus_f(float x){
  return (x > 20.f) ? x : log1pf(__expf(x));
}
__device__ __forceinline__ float logsig_f(float x){
  return -softplus_f(-x);
}
__device__ __forceinline__ unsigned short f2bf(float f){
  unsigned int u = __builtin_bit_cast(unsigned int, f);
  u += 0x7fffu + ((u >> 16) & 1u);
  return (unsigned short)(u >> 16);
}
__device__ __forceinline__ unsigned int packbf2(float a0, float a1){
  return (unsigned int)f2bf(a0) | ((unsigned int)f2bf(a1) << 16);
}

// ---------------- weight f32 -> bf16 conversion (33 slots of 192x192) ----------------
__global__ __launch_bounds__(256) void convert_w_k(
    const float* __restrict__ p0, const float* __restrict__ p1,
    const float* __restrict__ p2, const float* __restrict__ p3,
    const float* __restrict__ p4, const float* __restrict__ p5,
    const float* __restrict__ p6, unsigned short* __restrict__ Wb){
  int i = blockIdx.x*256 + threadIdx.x;
  const int total = 33*WSLOT;
  if (i >= total) return;
  int slot = i / WSLOT, r = i % WSLOT;
  const float* src;
  if      (slot == 0) src = p0 + r;
  else if (slot == 1) src = p1 + r;
  else if (slot == 2) src = p2 + r;
  else if (slot < 6)  src = p3 + (size_t)(slot-3)*WSLOT + r;
  else if (slot < 9)  src = p4 + (size_t)(slot-6)*WSLOT + r;
  else if (slot < 21) src = p5 + (size_t)(slot-9)*WSLOT + r;
  else                src = p6 + (size_t)(slot-21)*WSLOT + r;
  Wb[i] = f2bf(*src);
}

// ---------------- conv 192x192 (bf16 MFMA) over 32-t tile, epilogue modes ----------------
// mode 0: out = acc + bias ; mode 1: *mask ; mode 2: *mask + addsrc
__global__ __launch_bounds__(256) void conv_cc_k(
    const float* __restrict__ in, const unsigned short* __restrict__ Wb,
    const float* __restrict__ bias, const float* __restrict__ mask,
    const float* __restrict__ addsrc, float* __restrict__ out, int mode){
  __shared__ unsigned short bufX[32*200];    // bf16 [t][ci], stride 200
  int b = blockIdx.y, t0 = blockIdx.x*32;
  int tid = threadIdx.x;
  int tl = tid & 31, cs = tid >> 5;          // 8 c-groups of 24
  int c0 = cs*24;
  const float* inb = in + (size_t)b*CC*TTT + t0;
  #pragma unroll
  for (int j=0;j<12;j++){
    int c = c0 + 2*j;
    float f0 = inb[(size_t)c*TTT + tl];
    float f1 = inb[(size_t)(c+1)*TTT + tl];
    *(unsigned int*)&bufX[tl*200 + c] = packbf2(f0, f1);
  }
  __syncthreads();
  int w = tid >> 6, lane = tid & 63;
  int n16 = lane & 15, quad = lane >> 4;
  Frag af[3][6];
  #pragma unroll
  for (int ct=0; ct<3; ct++){
    int co = w*48 + ct*16 + n16;
    #pragma unroll
    for (int k=0;k<6;k++)
      af[ct][k].i = *(const int4*)(Wb + (size_t)co*CC + k*32 + quad*8);
  }
  floatx4 acc[3][2];
  #pragma unroll
  for (int ct=0;ct<3;ct++)
    #pragma unroll
    for (int tt=0;tt<2;tt++)
      acc[ct][tt] = (floatx4){0.f,0.f,0.f,0.f};
  #pragma unroll
  for (int k=0;k<6;k++){
    Frag bf[2];
    #pragma unroll
    for (int tt=0;tt<2;tt++)
      bf[tt].i = *(const int4*)&bufX[(tt*16+n16)*200 + k*32 + quad*8];
    #pragma unroll
    for (int ct=0;ct<3;ct++)
      #pragma unroll
      for (int tt=0;tt<2;tt++)
        acc[ct][tt] = __builtin_amdgcn_mfma_f32_16x16x32_bf16(af[ct][k].s, bf[tt].s, acc[ct][tt], 0,0,0);
  }
  // epilogue: D[m=quad*4+r][n=lane&15] -> co = w*48+ct*16+quad*4+r, t = tt*16+n16
  #pragma unroll
  for (int ct=0;ct<3;ct++){
    int cobase = w*48 + ct*16 + quad*4;
    float4 b4 = *(const float4*)(bias + cobase);
    float ba[4] = {b4.x, b4.y, b4.z, b4.w};
    #pragma unroll
    for (int tt=0;tt<2;tt++){
      int t = t0 + tt*16 + n16;
      float mv = (mode >= 1) ? mask[(size_t)b*TTT + t] : 1.f;
      #pragma unroll
      for (int r=0;r<4;r++){
        float v = acc[ct][tt][r] + ba[r];
        if (mode >= 1) v *= mv;
        if (mode == 2) v += addsrc[((size_t)b*CC + cobase + r)*TTT + t];
        out[((size_t)b*CC + cobase + r)*TTT + t] = v;
      }
    }
  }
}

// ---------------- DDS layer: depthwise -> LN -> gelu -> conv(MFMA) -> LN -> gelu -> +x ----------------
__global__ __launch_bounds__(256) void dds_layer_k(
    const float* __restrict__ in, float* __restrict__ out,
    const float* __restrict__ mask,
    const float* __restrict__ dw, const float* __restrict__ db,
    const float* __restrict__ g0, const float* __restrict__ b0,
    const unsigned short* __restrict__ Wb, const float* __restrict__ pb,
    const float* __restrict__ g1, const float* __restrict__ b1,
    int dil){
  __shared__ unsigned short bufX[32*200];   // bf16 [t][ci]
  __shared__ float buf2[32*193];            // f32 [t][co]
  __shared__ float redS[32*9], redQ[32*9];
  __shared__ float mst[32], rst[32];
  int b = blockIdx.y, t0 = blockIdx.x*32;
  int tid = threadIdx.x;
  int tl = tid & 31, cs = tid >> 5;
  int c0 = cs*24;
  int tg = t0 + tl;
  const float* inb = in + (size_t)b*CC*TTT;
  const float* mk  = mask + (size_t)b*TTT;
  float mc  = mk[tg];
  float mlv = (tg-dil >= 0)  ? mk[tg-dil] : 0.f;
  float mrv = (tg+dil < TTT) ? mk[tg+dil] : 0.f;
  // P1: depthwise into registers + stat partials
  float v[24];
  float s = 0.f, q = 0.f;
  #pragma unroll
  for (int j=0;j<24;j++){
    int c = c0 + j;
    const float* xr = inb + (size_t)c*TTT;
    float xl = (tg-dil >= 0)  ? xr[tg-dil]*mlv : 0.f;
    float xc = xr[tg]*mc;
    float xv = (tg+dil < TTT) ? xr[tg+dil]*mrv : 0.f;
    float val = fmaf(dw[c*3], xl, fmaf(dw[c*3+1], xc, fmaf(dw[c*3+2], xv, db[c])));
    v[j] = val; s += val; q = fmaf(val, val, q);
  }
  redS[tl*9+cs] = s; redQ[tl*9+cs] = q;
  __syncthreads();
  if (tid < 32){
    float S=0.f, Q=0.f;
    #pragma unroll
    for (int j=0;j<8;j++){ S += redS[tid*9+j]; Q += redQ[tid*9+j]; }
    float m = S*(1.f/CC);
    mst[tid] = m; rst[tid] = rsqrtf(Q*(1.f/CC) - m*m + 1e-5f);
  }
  __syncthreads();
  // P3: normalize + gelu -> bf16 LDS
  {
    float mm = mst[tl], rr = rst[tl];
    #pragma unroll
    for (int j=0;j<12;j++){
      int c = c0 + 2*j;
      float a0 = geluf((v[2*j]  -mm)*rr*g0[c]   + b0[c]);
      float a1 = geluf((v[2*j+1]-mm)*rr*g0[c+1] + b0[c+1]);
      *(unsigned int*)&bufX[tl*200 + c] = packbf2(a0, a1);
    }
  }
  __syncthreads();
  // P4: conv via MFMA
  int w = tid >> 6, lane = tid & 63;
  int n16 = lane & 15, quad = lane >> 4;
  {
    Frag af[3][6];
    #pragma unroll
    for (int ct=0; ct<3; ct++){
      int co = w*48 + ct*16 + n16;
      #pragma unroll
      for (int k=0;k<6;k++)
        af[ct][k].i = *(const int4*)(Wb + (size_t)co*CC + k*32 + quad*8);
    }
    floatx4 acc[3][2];
    #pragma unroll
    for (int ct=0;ct<3;ct++)
      #pragma unroll
      for (int tt=0;tt<2;tt++)
        acc[ct][tt] = (floatx4){0.f,0.f,0.f,0.f};
    #pragma unroll
    for (int k=0;k<6;k++){
      Frag bf[2];
      #pragma unroll
      for (int tt=0;tt<2;tt++)
        bf[tt].i = *(const int4*)&bufX[(tt*16+n16)*200 + k*32 + quad*8];
      #pragma unroll
      for (int ct=0;ct<3;ct++)
        #pragma unroll
        for (int tt=0;tt<2;tt++)
          acc[ct][tt] = __builtin_amdgcn_mfma_f32_16x16x32_bf16(af[ct][k].s, bf[tt].s, acc[ct][tt], 0,0,0);
    }
    #pragma unroll
    for (int ct=0;ct<3;ct++){
      int cobase = w*48 + ct*16 + quad*4;
      float4 b4 = *(const float4*)(pb + cobase);
      float ba[4] = {b4.x, b4.y, b4.z, b4.w};
      #pragma unroll
      for (int tt=0;tt<2;tt++){
        int t = tt*16 + n16;
        #pragma unroll
        for (int r=0;r<4;r++)
          buf2[t*193 + cobase + r] = acc[ct][tt][r] + ba[r];
      }
    }
  }
  __syncthreads();
  // P5: LN stats on conv output
  {
    float s2=0.f, q2=0.f;
    #pragma unroll
    for (int j=0;j<24;j++){
      float val = buf2[tl*193 + c0 + j];
      s2 += val; q2 = fmaf(val, val, q2);
    }
    redS[tl*9+cs] = s2; redQ[tl*9+cs] = q2;
  }
  __syncthreads();
  if (tid < 32){
    float S=0.f, Q=0.f;
    #pragma unroll
    for (int j=0;j<8;j++){ S += redS[tid*9+j]; Q += redQ[tid*9+j]; }
    float m = S*(1.f/CC);
    mst[tid] = m; rst[tid] = rsqrtf(Q*(1.f/CC) - m*m + 1e-5f);
  }
  __syncthreads();
  // P6: normalize + gelu + residual
  {
    float mm = mst[tl], rr = rst[tl];
    #pragma unroll
    for (int j=0;j<24;j++){
      int c = c0 + j;
      float val = (buf2[tl*193 + c] - mm)*rr*g1[c] + b1[c];
      out[((size_t)b*CC + c)*TTT + tg] = inb[(size_t)c*TTT + tg] + geluf(val);
    }
  }
}

// ---------------- rank-1 pre-conv ----------------
__global__ __launch_bounds__(256) void bcast_pre_k(
    const float* __restrict__ src, int sstride,
    const float* __restrict__ pwv, const float* __restrict__ pbv,
    const float* __restrict__ g, float* __restrict__ out){
  int b = blockIdx.y, t0 = blockIdx.x*64;
  int tid = threadIdx.x; int tl = tid & 63, cs = tid >> 6;
  float x0 = src[(size_t)b*sstride + t0 + tl];
  for (int j=0;j<48;j++){
    int c = cs*48 + j;
    float v = fmaf(pwv[c], x0, pbv[c]);
    if (g) v += g[((size_t)b*CC + c)*TTT + t0 + tl];
    out[((size_t)b*CC + c)*TTT + t0 + tl] = v;
  }
}

// ---------------- 29x192 projection, *mask ----------------
__global__ __launch_bounds__(256) void proj29_k(
    const float* __restrict__ in, const float* __restrict__ W,
    const float* __restrict__ bias, const float* __restrict__ mask,
    float* __restrict__ outp){
  __shared__ float xt[CC*64];
  int b = blockIdx.y, t0 = blockIdx.x*64;
  int tid = threadIdx.x; int tl = tid & 63, cs = tid >> 6;
  for (int j=0;j<48;j++){
    int ci = cs*48 + j;
    xt[ci*64 + tl] = in[((size_t)b*CC + ci)*TTT + t0 + tl];
  }
  __syncthreads();
  int co = tid & 31, tg8 = tid >> 5;
  if (co < PP){
    float acc[8];
    #pragma unroll
    for (int i=0;i<8;i++) acc[i]=bias[co];
    const float* Wr = W + (size_t)co*CC;
    for (int ci=0; ci<CC; ci+=4){
      float4 w4 = *(const float4*)(Wr+ci);
      float wa[4]={w4.x,w4.y,w4.z,w4.w};
      #pragma unroll
      for (int u=0;u<4;u++){
        const float* xr = &xt[(ci+u)*64 + tg8*8];
        float4 a  = *(const float4*)xr;
        float4 c4 = *(const float4*)(xr+4);
        acc[0]=fmaf(wa[u],a.x,acc[0]);  acc[1]=fmaf(wa[u],a.y,acc[1]);
        acc[2]=fmaf(wa[u],a.z,acc[2]);  acc[3]=fmaf(wa[u],a.w,acc[3]);
        acc[4]=fmaf(wa[u],c4.x,acc[4]); acc[5]=fmaf(wa[u],c4.y,acc[5]);
        acc[6]=fmaf(wa[u],c4.z,acc[6]); acc[7]=fmaf(wa[u],c4.w,acc[7]);
      }
    }
    #pragma unroll
    for (int k=0;k<8;k++){
      int t = tg8*8 + k;
      outp[((size_t)b*PP + co)*TTT + t0 + t] = acc[k]*mask[(size_t)b*TTT + t0 + t];
    }
  }
}

// ---------------- RQS spline coupling ----------------
__global__ __launch_bounds__(256) void spline_k(
    float* __restrict__ z, int s, const float* __restrict__ proj,
    const float* __restrict__ mask, float* __restrict__ acc){
  __shared__ float red[256];
  int b = blockIdx.y; int t = blockIdx.x*256 + threadIdx.x;
  const float scv = 0.07216878364870323f;   // 1/sqrt(192)
  float m = mask[(size_t)b*TTT + t];
  float* z0p = z + ((size_t)b*2 + s)*TTT + t;
  float* z1p = z + ((size_t)b*2 + (1-s))*TTT + t;
  float xs = *z1p;
  const float* hp = proj + (size_t)b*PP*TTT + t;
  float uw[10], uh[10], ud[9];
  #pragma unroll
  for (int k=0;k<10;k++) uw[k]=hp[(size_t)k*TTT]*scv;
  #pragma unroll
  for (int k=0;k<10;k++) uh[k]=hp[(size_t)(10+k)*TTT]*scv;
  #pragma unroll
  for (int k=0;k<9;k++)  ud[k]=hp[(size_t)(20+k)*TTT];
  bool inside = (xs >= -5.f) && (xs <= 5.f);
  float xc = fminf(fmaxf(xs,-5.f),5.f);
  float mx=uw[0];
  #pragma unroll
  for (int k=1;k<10;k++) mx=fmaxf(mx,uw[k]);
  float sw=0.f; float wd[10];
  #pragma unroll
  for (int k=0;k<10;k++){ wd[k]=__expf(uw[k]-mx); sw+=wd[k]; }
  float invw = 1.f/sw;
  #pragma unroll
  for (int k=0;k<10;k++) wd[k]=fmaf(0.99f*invw, wd[k], 1e-3f);
  float mh=uh[0];
  #pragma unroll
  for (int k=1;k<10;k++) mh=fmaxf(mh,uh[k]);
  float sh=0.f; float ht[10];
  #pragma unroll
  for (int k=0;k<10;k++){ ht[k]=__expf(uh[k]-mh); sh+=ht[k]; }
  float invh = 1.f/sh;
  #pragma unroll
  for (int k=0;k<10;k++) ht[k]=fmaf(0.99f*invh, ht[k], 1e-3f);
  float cw=-5.f, icw=-5.f, iw=1.f; int idx=0;
  #pragma unroll
  for (int i=0;i<10;i++){
    float nw = (i==9) ? 5.f : fmaf(10.f, wd[i], cw);
    if (cw <= xc){ idx=i; icw=cw; iw=nw-cw; }
    cw=nw;
  }
  float ch=-5.f, ich=-5.f, ih=1.f;
  #pragma unroll
  for (int i=0;i<10;i++){
    float nh = (i==9) ? 5.f : fmaf(10.f, ht[i], ch);
    if (i==idx){ ich=ch; ih=nh-ch; }
    ch=nh;
  }
  const float UDC = logf(expm1f(0.999f));
  float d0=1.f, d1=1.f;
  #pragma unroll
  for (int k=0;k<11;k++){
    float uu = (k==0 || k==10) ? UDC : ud[k-1];
    float dk = 1e-3f + softplus_f(uu);
    if (k==idx)   d0=dk;
    if (k==idx+1) d1=dk;
  }
  float idel = ih/iw;
  float th = (xc-icw)/iw;
  float t1m = th*(1.f-th);
  float den = idel + (d0+d1-2.f*idel)*t1m;
  float outv = ich + ih*(idel*th*th + d0*t1m)/den;
  float omt = 1.f-th;
  float dnum = idel*idel*(d1*th*th + 2.f*idel*t1m + d0*omt*omt);
  float lad = logf(dnum) - 2.f*logf(den);
  float y = inside ? outv : xs;
  lad = inside ? lad : 0.f;
  *z1p = y*m;
  *z0p = (*z0p)*m;
  int tid = threadIdx.x;
  red[tid] = lad*m;
  __syncthreads();
  for (int o=128;o>0;o>>=1){ if (tid<o) red[tid]+=red[tid+o]; __syncthreads(); }
  if (tid==0) atomicAdd(acc+b, -red[0]);
}

// ---------------- z init ----------------
__global__ __launch_bounds__(256) void init_z_k(
    const float* __restrict__ e_q, const float* __restrict__ mask,
    const float* __restrict__ pm, const float* __restrict__ pl,
    float* __restrict__ z, float* __restrict__ acc){
  __shared__ float red[256];
  int b = blockIdx.y; int t = blockIdx.x*256 + threadIdx.x;
  float m = mask[(size_t)b*TTT + t];
  float pl0=pl[0], pl1=pl[1];
  float e0 = e_q[((size_t)b*2+0)*TTT + t]*m;
  float e1 = e_q[((size_t)b*2+1)*TTT + t]*m;
  z[((size_t)b*2+0)*TTT + t] = fmaf(__expf(pl0), e0, pm[0])*m;
  z[((size_t)b*2+1)*TTT + t] = fmaf(__expf(pl1), e1, pm[1])*m;
  float contrib = -0.5f*(LOG2PI_F + e0*e0)*m - 0.5f*(LOG2PI_F + e1*e1)*m - (pl0+pl1)*m;
  int tid = threadIdx.x;
  red[tid] = contrib;
  __syncthreads();
  for (int o=128;o>0;o>>=1){ if (tid<o) red[tid]+=red[tid+o]; __syncthreads(); }
  if (tid==0) atomicAdd(acc+b, red[0]);
}

// ---------------- between p-flows and f-flows ----------------
__global__ __launch_bounds__(256) void final_pre_k(
    float* __restrict__ z, const float* __restrict__ w_in, const float* __restrict__ mask,
    const float* __restrict__ am, const float* __restrict__ al, float* __restrict__ acc){
  __shared__ float red[256];
  int b = blockIdx.y; int t = blockIdx.x*256 + threadIdx.x;
  float m = mask[(size_t)b*TTT + t];
  float zu  = z[((size_t)b*2+0)*TTT + t];
  float z1v = z[((size_t)b*2+1)*TTT + t];
  float wv  = w_in[(size_t)b*TTT + t];
  float u  = m / (1.f + __expf(-zu));
  float z0 = (wv - u)*m;
  float y0 = logf(fmaxf(z0, 1e-5f))*m;
  float al0=al[0], al1=al[1];
  z[((size_t)b*2+0)*TTT + t] = fmaf(__expf(al0), y0,  am[0])*m;
  z[((size_t)b*2+1)*TTT + t] = fmaf(__expf(al1), z1v, am[1])*m;
  float contrib = -(logsig_f(zu)+logsig_f(-zu))*m + y0 - (al0+al1)*m;
  int tid = threadIdx.x;
  red[tid] = contrib;
  __syncthreads();
  for (int o=128;o>0;o>>=1){ if (tid<o) red[tid]+=red[tid+o]; __syncthreads(); }
  if (tid==0) atomicAdd(acc+b, red[0]);
}

// ---------------- final 0.5(log2pi + z^2) sum ----------------
__global__ __launch_bounds__(256) void final_post_k(
    const float* __restrict__ z, const float* __restrict__ mask, float* __restrict__ acc){
  __shared__ float red[256];
  int b = blockIdx.y; int t = blockIdx.x*256 + threadIdx.x;
  float m = mask[(size_t)b*TTT + t];
  float z0 = z[((size_t)b*2+0)*TTT + t];
  float z1 = z[((size_t)b*2+1)*TTT + t];
  float contrib = 0.5f*(LOG2PI_F + z0*z0)*m + 0.5f*(LOG2PI_F + z1*z1)*m;
  int tid = threadIdx.x;
  red[tid] = contrib;
  __syncthreads();
  for (int o=128;o>0;o>>=1){ if (tid<o) red[tid]+=red[tid+o]; __syncthreads(); }
  if (tid==0) atomicAdd(acc+b, red[0]);
}

__global__ void write_out_k(const float* __restrict__ acc, float* __restrict__ out, int n){
  int i = threadIdx.x;
  if (i < n) out[i] = acc[i];
}

extern "C" void kernel_launch(void* const* d_in, const int* in_sizes, int n_in,
                              void* d_out, int out_size, void* d_ws, size_t ws_size,
                              hipStream_t stream){
  (void)n_in; (void)out_size; (void)ws_size;
  const float* x         = (const float*)d_in[0];
  const float* mask      = (const float*)d_in[1];
  const float* w_in      = (const float*)d_in[2];
  const float* e_q       = (const float*)d_in[3];
  const float* pre_w     = (const float*)d_in[4];
  const float* pre_b     = (const float*)d_in[5];
  const float* proj_w    = (const float*)d_in[6];
  const float* proj_b    = (const float*)d_in[7];
  const float* dds_dep_w = (const float*)d_in[8];
  const float* dds_dep_b = (const float*)d_in[9];
  const float* dds_pw_w  = (const float*)d_in[10];
  const float* dds_pw_b  = (const float*)d_in[11];
  const float* dds_ln_g  = (const float*)d_in[12];
  const float* dds_ln_b  = (const float*)d_in[13];
  const float* post_pre_w  = (const float*)d_in[14];
  const float* post_pre_b  = (const float*)d_in[15];
  const float* post_proj_w = (const float*)d_in[16];
  const float* post_proj_b = (const float*)d_in[17];
  const float* pdds_dep_w  = (const float*)d_in[18];
  const float* pdds_dep_b  = (const float*)d_in[19];
  const float* pdds_pw_w   = (const float*)d_in[20];
  const float* pdds_pw_b   = (const float*)d_in[21];
  const float* pdds_ln_g   = (const float*)d_in[22];
  const float* pdds_ln_b   = (const float*)d_in[23];
  const float* aff_m    = (const float*)d_in[24];
  const float* aff_logs = (const float*)d_in[25];
  const float* f_pre_w  = (const float*)d_in[26];
  const float* f_pre_b  = (const float*)d_in[27];
  const float* f_dep_w  = (const float*)d_in[28];
  const float* f_dep_b  = (const float*)d_in[29];
  const float* f_pw_w   = (const float*)d_in[30];
  const float* f_pw_b   = (const float*)d_in[31];
  const float* f_ln_g   = (const float*)d_in[32];
  const float* f_ln_b   = (const float*)d_in[33];
  const float* f_proj_w = (const float*)d_in[34];
  const float* f_proj_b = (const float*)d_in[35];
  const float* paff_m    = (const float*)d_in[36];
  const float* paff_logs = (const float*)d_in[37];
  const float* p_pre_w  = (const float*)d_in[38];
  const float* p_pre_b  = (const float*)d_in[39];
  const float* p_dep_w  = (const float*)d_in[40];
  const float* p_dep_b  = (const float*)d_in[41];
  const float* p_pw_w   = (const float*)d_in[42];
  const float* p_pw_b   = (const float*)d_in[43];
  const float* p_ln_g   = (const float*)d_in[44];
  const float* p_ln_b   = (const float*)d_in[45];
  const float* p_proj_w = (const float*)d_in[46];
  const float* p_proj_b = (const float*)d_in[47];

  int Bn = in_sizes[0] / (CC*TTT);
  size_t big = (size_t)Bn*CC*TTT;
  float* A    = (float*)d_ws;
  float* Bb   = A + big;
  float* H    = Bb + big;
  float* GP   = H + big;
  float* pbuf = GP + big;
  float* zbuf = pbuf + (size_t)Bn*PP*TTT;
  float* acc  = zbuf + (size_t)Bn*2*TTT;
  unsigned short* Wb = (unsigned short*)(acc + ((Bn + 3) & ~3));

  hipMemsetAsync(acc, 0, Bn*sizeof(float), stream);
  convert_w_k<<<(33*WSLOT + 255)/256, 256, 0, stream>>>(
      pre_w, proj_w, post_proj_w, dds_pw_w, pdds_pw_w, p_pw_w, f_pw_w, Wb);

  dim3 g32(TTT/32, Bn), g64(TTT/64, Bn), g256(TTT/256, Bn);
  dim3 b256(256);

  // bf16 weight slots
  unsigned short* W_pre      = Wb + 0*(size_t)WSLOT;
  unsigned short* W_proj     = Wb + 1*(size_t)WSLOT;
  unsigned short* W_postproj = Wb + 2*(size_t)WSLOT;
  unsigned short* W_dds      = Wb + 3*(size_t)WSLOT;   // 3 slots
  unsigned short* W_pdds     = Wb + 6*(size_t)WSLOT;   // 3 slots
  unsigned short* W_ppw      = Wb + 9*(size_t)WSLOT;   // 12 slots
  unsigned short* W_fpw      = Wb + 21*(size_t)WSLOT;  // 12 slots

  auto dds3 = [&](const float* dep_w, const float* dep_b, unsigned short* Wslots,
                  const float* pw_b, const float* ln_g, const float* ln_b,
                  float* bin, float* bout){
    const int dils[3] = {1,3,9};
    const float* src[3] = {bin, bout, bin};
    float* dst[3]       = {bout, bin, bout};
    for (int i=0;i<3;i++){
      dds_layer_k<<<g32, b256, 0, stream>>>(src[i], dst[i], mask,
        dep_w + (size_t)i*CC*3, dep_b + (size_t)i*CC,
        ln_g + (size_t)(i*2+0)*CC, ln_b + (size_t)(i*2+0)*CC,
        Wslots + (size_t)i*WSLOT, pw_b + (size_t)i*CC,
        ln_g + (size_t)(i*2+1)*CC, ln_b + (size_t)(i*2+1)*CC, dils[i]);
    }
  };

  // ---- h path ----
  conv_cc_k<<<g32, b256, 0, stream>>>(x, W_pre, pre_b, mask, nullptr, A, 0);
  dds3(dds_dep_w, dds_dep_b, W_dds, dds_pw_b, dds_ln_g, dds_ln_b, A, Bb);
  conv_cc_k<<<g32, b256, 0, stream>>>(Bb, W_proj, proj_b, mask, nullptr, H, 1);

  // ---- hw path ----
  bcast_pre_k<<<g64, b256, 0, stream>>>(w_in, TTT, post_pre_w, post_pre_b, nullptr, A);
  dds3(pdds_dep_w, pdds_dep_b, W_pdds, pdds_pw_b, pdds_ln_g, pdds_ln_b, A, Bb);
  conv_cc_k<<<g32, b256, 0, stream>>>(Bb, W_postproj, post_proj_b, mask, H, GP, 2);

  // ---- init z from e_q ----
  init_z_k<<<g256, b256, 0, stream>>>(e_q, mask, paff_m, paff_logs, zbuf, acc);

  // ---- 4 posterior flows (g = GP) ----
  for (int f=0; f<4; f++){
    int s = f & 1;
    bcast_pre_k<<<g64, b256, 0, stream>>>(zbuf + (size_t)s*TTT, 2*TTT,
        p_pre_w + (size_t)f*CC, p_pre_b + (size_t)f*CC, GP, A);
    dds3(p_dep_w + (size_t)f*3*CC*3, p_dep_b + (size_t)f*3*CC,
         W_ppw + (size_t)f*3*WSLOT, p_pw_b + (size_t)f*3*CC,
         p_ln_g + (size_t)f*3*2*CC, p_ln_b + (size_t)f*3*2*CC, A, Bb);
    proj29_k<<<g64, b256, 0, stream>>>(Bb, p_proj_w + (size_t)f*PP*CC,
        p_proj_b + (size_t)f*PP, mask, pbuf);
    spline_k<<<g256, b256, 0, stream>>>(zbuf, s, pbuf, mask, acc);
  }

  // ---- transition ----
  final_pre_k<<<g256, b256, 0, stream>>>(zbuf, w_in, mask, aff_m, aff_logs, acc);

  // ---- 4 flows (g = H) ----
  for (int f=0; f<4; f++){
    int s = f & 1;
    bcast_pre_k<<<g64, b256, 0, stream>>>(zbuf + (size_t)s*TTT, 2*TTT,
        f_pre_w + (size_t)f*CC, f_pre_b + (size_t)f*CC, H, A);
    dds3(f_dep_w + (size_t)f*3*CC*3, f_dep_b + (size_t)f*3*CC,
         W_fpw + (size_t)f*3*WSLOT, f_pw_b + (size_t)f*3*CC,
         f_ln_g + (size_t)f*3*2*CC, f_ln_b + (size_t)f*3*2*CC, A, Bb);
    proj29_k<<<g64, b256, 0, stream>>>(Bb, f_proj_w + (size_t)f*PP*CC,
        f_proj_b + (size_t)f*PP, mask, pbuf);
    spline_k<<<g256, b256, 0, stream>>>(zbuf, s, pbuf, mask, acc);
  }

  final_post_k<<<g256, b256, 0, stream>>>(zbuf, mask, acc);
  write_out_k<<<1, 64, 0, stream>>>(acc, (float*)d_out, Bn);
}

// Round 3
// 1203.401 us; speedup vs baseline: 2.3732x; 2.1247x over previous
//
#include <hip/hip_runtime.h>
#include <math.h>

#define CC 192
#define TTT 768
#define PP 29
#define LOG2PI_F 1.8378770664093453f
#define WSLOT 36864   // 192*192

typedef __attribute__((ext_vector_type(8))) short short8;
typedef __attribute__((ext_vector_type(4))) float floatx4;
union Frag { int4 i; short8 s; };

__device__ __forceinline__ float geluf(float x){
  float u = 1.5957691216057308f * (x + 0.044715f*x*x*x);
  return x * __builtin_amdgcn_rcpf(1.f + __expf(-u));
}
__device__ __forceinline__ float softplus_f(float x){
  return (x > 20.f) ? x : log1pf(__expf(x));
}
__device__ __forceinline__ float logsig_f(float x){
  return -softplus_f(-x);
}
__device__ __forceinline__ unsigned short f2bf(float f){
  unsigned int u = __builtin_bit_cast(unsigned int, f);
  u += 0x7fffu + ((u >> 16) & 1u);
  return (unsigned short)(u >> 16);
}
__device__ __forceinline__ unsigned int packbf2(float a0, float a1){
  return (unsigned int)f2bf(a0) | ((unsigned int)f2bf(a1) << 16);
}

// ---------------- weight f32 -> bf16 conversion (33 slots of 192x192) ----------------
__global__ __launch_bounds__(256) void convert_w_k(
    const float* __restrict__ p0, const float* __restrict__ p1,
    const float* __restrict__ p2, const float* __restrict__ p3,
    const float* __restrict__ p4, const float* __restrict__ p5,
    const float* __restrict__ p6, unsigned short* __restrict__ Wb){
  int i = blockIdx.x*256 + threadIdx.x;
  const int total = 33*WSLOT;
  if (i >= total) return;
  int slot = i / WSLOT, r = i % WSLOT;
  const float* src;
  if      (slot == 0) src = p0 + r;
  else if (slot == 1) src = p1 + r;
  else if (slot == 2) src = p2 + r;
  else if (slot < 6)  src = p3 + (size_t)(slot-3)*WSLOT + r;
  else if (slot < 9)  src = p4 + (size_t)(slot-6)*WSLOT + r;
  else if (slot < 21) src = p5 + (size_t)(slot-9)*WSLOT + r;
  else                src = p6 + (size_t)(slot-21)*WSLOT + r;
  Wb[i] = f2bf(*src);
}

// ---------------- conv 192x192 (bf16 MFMA) over 32-t tile, epilogue modes ----------------
__global__ __launch_bounds__(256) void conv_cc_k(
    const float* __restrict__ in, const unsigned short* __restrict__ Wb,
    const float* __restrict__ bias, const float* __restrict__ mask,
    const float* __restrict__ addsrc, float* __restrict__ out, int mode){
  __shared__ unsigned short bufX[32*200];
  int b = blockIdx.y, t0 = blockIdx.x*32;
  int tid = threadIdx.x;
  int tl = tid & 31, cs = tid >> 5;
  int c0 = cs*24;
  const float* inb = in + (size_t)b*CC*TTT + t0;
  #pragma unroll
  for (int j=0;j<12;j++){
    int c = c0 + 2*j;
    float f0 = inb[(size_t)c*TTT + tl];
    float f1 = inb[(size_t)(c+1)*TTT + tl];
    *(unsigned int*)&bufX[tl*200 + c] = packbf2(f0, f1);
  }
  __syncthreads();
  int w = tid >> 6, lane = tid & 63;
  int n16 = lane & 15, quad = lane >> 4;
  Frag af[3][6];
  #pragma unroll
  for (int ct=0; ct<3; ct++){
    int co = w*48 + ct*16 + n16;
    #pragma unroll
    for (int k=0;k<6;k++)
      af[ct][k].i = *(const int4*)(Wb + (size_t)co*CC + k*32 + quad*8);
  }
  floatx4 acc[3][2];
  #pragma unroll
  for (int ct=0;ct<3;ct++)
    #pragma unroll
    for (int tt=0;tt<2;tt++)
      acc[ct][tt] = (floatx4){0.f,0.f,0.f,0.f};
  #pragma unroll
  for (int k=0;k<6;k++){
    Frag bf[2];
    #pragma unroll
    for (int tt=0;tt<2;tt++)
      bf[tt].i = *(const int4*)&bufX[(tt*16+n16)*200 + k*32 + quad*8];
    #pragma unroll
    for (int ct=0;ct<3;ct++)
      #pragma unroll
      for (int tt=0;tt<2;tt++)
        acc[ct][tt] = __builtin_amdgcn_mfma_f32_16x16x32_bf16(af[ct][k].s, bf[tt].s, acc[ct][tt], 0,0,0);
  }
  #pragma unroll
  for (int ct=0;ct<3;ct++){
    int cobase = w*48 + ct*16 + quad*4;
    float4 b4 = *(const float4*)(bias + cobase);
    float ba[4] = {b4.x, b4.y, b4.z, b4.w};
    #pragma unroll
    for (int tt=0;tt<2;tt++){
      int t = t0 + tt*16 + n16;
      float mv = (mode >= 1) ? mask[(size_t)b*TTT + t] : 1.f;
      #pragma unroll
      for (int r=0;r<4;r++){
        float v = acc[ct][tt][r] + ba[r];
        if (mode >= 1) v *= mv;
        if (mode == 2) v += addsrc[((size_t)b*CC + cobase + r)*TTT + t];
        out[((size_t)b*CC + cobase + r)*TTT + t] = v;
      }
    }
  }
}

// ---------------- fused DDS layer ----------------
// srcmode 0: x from `in` buffer ; srcmode 1: x[c][t] = pw1[c]*src1[t]+pb1[c] (+ g[c][t])
// outmode 0: write residual output to `out`
// outmode 1: proj(29x192 bf16 MFMA) + RQS spline, update z planes + acc
__global__ __launch_bounds__(256) void dds_fused_k(
    const float* __restrict__ in,
    const float* __restrict__ src1, int s1s,
    const float* __restrict__ pw1, const float* __restrict__ pb1,
    const float* __restrict__ g,
    float* __restrict__ out,
    const float* __restrict__ mask,
    const float* __restrict__ dw, const float* __restrict__ db,
    const float* __restrict__ g0, const float* __restrict__ b0,
    const unsigned short* __restrict__ Wb, const float* __restrict__ pb,
    const float* __restrict__ g1, const float* __restrict__ b1,
    int dil, int srcmode, int outmode,
    const float* __restrict__ projW, const float* __restrict__ projB,
    float* __restrict__ z, int zs, float* __restrict__ acco){
  __shared__ unsigned short bufX[32*200];   // bf16 [t][ci]
  __shared__ float buf2[32*193];            // f32 [t][co]
  __shared__ float par[2112];               // dw(576) db g0 b0 g1 b1 pw1 pb1 pb
  __shared__ float redS[32*9], redQ[32*9];
  __shared__ float mst[32], rst[32];
  __shared__ float pro[32*30];
  int b = blockIdx.y, t0 = blockIdx.x*32;
  int tid = threadIdx.x;
  int tl = tid & 31, cs = tid >> 5;
  int c0 = cs*24;
  int tg = t0 + tl;
  // stage per-channel params
  for (int i=tid; i<576; i+=256) par[i] = dw[i];
  if (tid < 192){
    par[576+tid]  = db[tid];
    par[768+tid]  = g0[tid];
    par[960+tid]  = b0[tid];
    par[1152+tid] = g1[tid];
    par[1344+tid] = b1[tid];
    par[1920+tid] = pb[tid];
    if (srcmode == 1){ par[1536+tid] = pw1[tid]; par[1728+tid] = pb1[tid]; }
  }
  const float* mk = mask + (size_t)b*TTT;
  int tlo = tg - dil, thi = tg + dil;
  int tloC = tlo < 0 ? 0 : tlo;
  int thiC = thi >= TTT ? TTT-1 : thi;
  float mc  = mk[tg];
  float mlv = mk[tloC] * (tlo >= 0 ? 1.f : 0.f);
  float mrv = mk[thiC] * (thi < TTT ? 1.f : 0.f);
  __syncthreads();
  // P1: depthwise, unconditional clamped loads
  float v[24], xcen[24];
  float s = 0.f, q = 0.f;
  if (srcmode == 0){
    const float* inb = in + (size_t)b*CC*TTT;
    #pragma unroll
    for (int j=0;j<24;j++){
      int c = c0 + j;
      const float* xr = inb + (size_t)c*TTT;
      float xl = xr[tloC], xc = xr[tg], xh = xr[thiC];
      xcen[j] = xc;
      float val = fmaf(par[c*3], xl*mlv, fmaf(par[c*3+1], xc*mc,
                  fmaf(par[c*3+2], xh*mrv, par[576+c])));
      v[j] = val; s += val; q = fmaf(val, val, q);
    }
  } else {
    const float* s1b = src1 + (size_t)b*s1s;
    float zl = s1b[tloC], zc = s1b[tg], zr = s1b[thiC];
    const float* gb = g ? (g + (size_t)b*CC*TTT) : nullptr;
    #pragma unroll
    for (int j=0;j<24;j++){
      int c = c0 + j;
      float pwc = par[1536+c], pbc = par[1728+c];
      float xl = fmaf(pwc, zl, pbc);
      float xc = fmaf(pwc, zc, pbc);
      float xh = fmaf(pwc, zr, pbc);
      if (gb){
        const float* gr = gb + (size_t)c*TTT;
        xl += gr[tloC]; xc += gr[tg]; xh += gr[thiC];
      }
      xcen[j] = xc;
      float val = fmaf(par[c*3], xl*mlv, fmaf(par[c*3+1], xc*mc,
                  fmaf(par[c*3+2], xh*mrv, par[576+c])));
      v[j] = val; s += val; q = fmaf(val, val, q);
    }
  }
  redS[tl*9+cs] = s; redQ[tl*9+cs] = q;
  __syncthreads();
  if (tid < 32){
    float S=0.f, Q=0.f;
    #pragma unroll
    for (int j=0;j<8;j++){ S += redS[tid*9+j]; Q += redQ[tid*9+j]; }
    float m = S*(1.f/CC);
    mst[tid] = m; rst[tid] = rsqrtf(Q*(1.f/CC) - m*m + 1e-5f);
  }
  __syncthreads();
  // P3: LN + gelu -> bf16
  {
    float mm = mst[tl], rr = rst[tl];
    #pragma unroll
    for (int j=0;j<12;j++){
      int c = c0 + 2*j;
      float a0 = geluf((v[2*j]  -mm)*rr*par[768+c]   + par[960+c]);
      float a1 = geluf((v[2*j+1]-mm)*rr*par[768+c+1] + par[960+c+1]);
      *(unsigned int*)&bufX[tl*200 + c] = packbf2(a0, a1);
    }
  }
  __syncthreads();
  // P4: conv via MFMA
  int w = tid >> 6, lane = tid & 63;
  int n16 = lane & 15, quad = lane >> 4;
  {
    Frag af[3][6];
    #pragma unroll
    for (int ct=0; ct<3; ct++){
      int co = w*48 + ct*16 + n16;
      #pragma unroll
      for (int k=0;k<6;k++)
        af[ct][k].i = *(const int4*)(Wb + (size_t)co*CC + k*32 + quad*8);
    }
    floatx4 acc[3][2];
    #pragma unroll
    for (int ct=0;ct<3;ct++)
      #pragma unroll
      for (int tt=0;tt<2;tt++)
        acc[ct][tt] = (floatx4){0.f,0.f,0.f,0.f};
    #pragma unroll
    for (int k=0;k<6;k++){
      Frag bf[2];
      #pragma unroll
      for (int tt=0;tt<2;tt++)
        bf[tt].i = *(const int4*)&bufX[(tt*16+n16)*200 + k*32 + quad*8];
      #pragma unroll
      for (int ct=0;ct<3;ct++)
        #pragma unroll
        for (int tt=0;tt<2;tt++)
          acc[ct][tt] = __builtin_amdgcn_mfma_f32_16x16x32_bf16(af[ct][k].s, bf[tt].s, acc[ct][tt], 0,0,0);
    }
    #pragma unroll
    for (int ct=0;ct<3;ct++){
      int cobase = w*48 + ct*16 + quad*4;
      #pragma unroll
      for (int tt=0;tt<2;tt++){
        int t = tt*16 + n16;
        #pragma unroll
        for (int r=0;r<4;r++)
          buf2[t*193 + cobase + r] = acc[ct][tt][r] + par[1920+cobase+r];
      }
    }
  }
  __syncthreads();
  // P5: LN stats
  {
    float s2=0.f, q2=0.f;
    #pragma unroll
    for (int j=0;j<24;j++){
      float val = buf2[tl*193 + c0 + j];
      s2 += val; q2 = fmaf(val, val, q2);
    }
    redS[tl*9+cs] = s2; redQ[tl*9+cs] = q2;
  }
  __syncthreads();
  if (tid < 32){
    float S=0.f, Q=0.f;
    #pragma unroll
    for (int j=0;j<8;j++){ S += redS[tid*9+j]; Q += redQ[tid*9+j]; }
    float m = S*(1.f/CC);
    mst[tid] = m; rst[tid] = rsqrtf(Q*(1.f/CC) - m*m + 1e-5f);
  }
  __syncthreads();
  // P6: LN + gelu + residual
  if (outmode == 0){
    float mm = mst[tl], rr = rst[tl];
    #pragma unroll
    for (int j=0;j<24;j++){
      int c = c0 + j;
      float val = (buf2[tl*193 + c] - mm)*rr*par[1152+c] + par[1344+c];
      out[((size_t)b*CC + c)*TTT + tg] = xcen[j] + geluf(val);
    }
    return;
  }
  // outmode 1: h -> bf16 bufX, then proj MFMA + spline
  {
    float mm = mst[tl], rr = rst[tl];
    #pragma unroll
    for (int j=0;j<12;j++){
      int c = c0 + 2*j;
      float v0 = (buf2[tl*193 + c]   - mm)*rr*par[1152+c]   + par[1344+c];
      float v1 = (buf2[tl*193 + c+1] - mm)*rr*par[1152+c+1] + par[1344+c+1];
      float h0 = xcen[2*j]   + geluf(v0);
      float h1 = xcen[2*j+1] + geluf(v1);
      *(unsigned int*)&bufX[tl*200 + c] = packbf2(h0, h1);
    }
  }
  __syncthreads();
  // proj: 2 co-tiles (0..15,16..31; rows>=29 garbage, ignored)
  {
    Frag af2[2][6];
    #pragma unroll
    for (int ct=0; ct<2; ct++){
      int co = ct*16 + n16; if (co > PP-1) co = PP-1;
      #pragma unroll
      for (int k=0;k<6;k++){
        const float* wr = projW + (size_t)co*CC + k*32 + quad*8;
        float4 a = *(const float4*)wr;
        float4 c4 = *(const float4*)(wr+4);
        unsigned int* pi = (unsigned int*)&af2[ct][k];
        pi[0]=packbf2(a.x,a.y); pi[1]=packbf2(a.z,a.w);
        pi[2]=packbf2(c4.x,c4.y); pi[3]=packbf2(c4.z,c4.w);
      }
    }
    floatx4 acc2[2][2];
    #pragma unroll
    for (int ct=0;ct<2;ct++)
      #pragma unroll
      for (int tt=0;tt<2;tt++)
        acc2[ct][tt] = (floatx4){0.f,0.f,0.f,0.f};
    #pragma unroll
    for (int k=0;k<6;k++){
      Frag bf[2];
      #pragma unroll
      for (int tt=0;tt<2;tt++)
        bf[tt].i = *(const int4*)&bufX[(tt*16+n16)*200 + k*32 + quad*8];
      #pragma unroll
      for (int ct=0;ct<2;ct++)
        #pragma unroll
        for (int tt=0;tt<2;tt++)
          acc2[ct][tt] = __builtin_amdgcn_mfma_f32_16x16x32_bf16(af2[ct][k].s, bf[tt].s, acc2[ct][tt], 0,0,0);
    }
    // only wave 0 (w==0) results are needed? No: all waves computed identical co-tiles?
    // Each wave computed the same A (co 0..31) and same B (t 0..31) -> identical results.
    // Let wave 0 write.
    if (w == 0){
      #pragma unroll
      for (int ct=0;ct<2;ct++){
        int cobase = ct*16 + quad*4;
        #pragma unroll
        for (int tt=0;tt<2;tt++){
          int t = tt*16 + n16;
          float mv = mk[t0 + t];
          #pragma unroll
          for (int r=0;r<4;r++){
            int co = cobase + r;
            if (co < PP) pro[t*30 + co] = (acc2[ct][tt][r] + projB[co]) * mv;
          }
        }
      }
    }
  }
  __syncthreads();
  // spline on 32 lanes
  float ladm = 0.f;
  if (tid < 32){
    const float scv = 0.07216878364870323f;   // 1/sqrt(192)
    float m = mc;
    float* z0p = z + ((size_t)b*2 + zs)*TTT + tg;
    float* z1p = z + ((size_t)b*2 + (1-zs))*TTT + tg;
    float xs = *z1p;
    float uw[10], uh[10], ud[9];
    #pragma unroll
    for (int k=0;k<10;k++) uw[k]=pro[tl*30+k]*scv;
    #pragma unroll
    for (int k=0;k<10;k++) uh[k]=pro[tl*30+10+k]*scv;
    #pragma unroll
    for (int k=0;k<9;k++)  ud[k]=pro[tl*30+20+k];
    bool inside = (xs >= -5.f) && (xs <= 5.f);
    float xc = fminf(fmaxf(xs,-5.f),5.f);
    float mx=uw[0];
    #pragma unroll
    for (int k=1;k<10;k++) mx=fmaxf(mx,uw[k]);
    float sw=0.f; float wd[10];
    #pragma unroll
    for (int k=0;k<10;k++){ wd[k]=__expf(uw[k]-mx); sw+=wd[k]; }
    float invw = 1.f/sw;
    #pragma unroll
    for (int k=0;k<10;k++) wd[k]=fmaf(0.99f*invw, wd[k], 1e-3f);
    float mh=uh[0];
    #pragma unroll
    for (int k=1;k<10;k++) mh=fmaxf(mh,uh[k]);
    float sh=0.f; float ht[10];
    #pragma unroll
    for (int k=0;k<10;k++){ ht[k]=__expf(uh[k]-mh); sh+=ht[k]; }
    float invh = 1.f/sh;
    #pragma unroll
    for (int k=0;k<10;k++) ht[k]=fmaf(0.99f*invh, ht[k], 1e-3f);
    float cw=-5.f, icw=-5.f, iw=1.f; int idx=0;
    #pragma unroll
    for (int i=0;i<10;i++){
      float nw = (i==9) ? 5.f : fmaf(10.f, wd[i], cw);
      if (cw <= xc){ idx=i; icw=cw; iw=nw-cw; }
      cw=nw;
    }
    float ch=-5.f, ich=-5.f, ih=1.f;
    #pragma unroll
    for (int i=0;i<10;i++){
      float nh = (i==9) ? 5.f : fmaf(10.f, ht[i], ch);
      if (i==idx){ ich=ch; ih=nh-ch; }
      ch=nh;
    }
    const float UDC = logf(expm1f(0.999f));
    float d0=1.f, d1=1.f;
    #pragma unroll
    for (int k=0;k<11;k++){
      float uu = (k==0 || k==10) ? UDC : ud[k-1];
      float dk = 1e-3f + softplus_f(uu);
      if (k==idx)   d0=dk;
      if (k==idx+1) d1=dk;
    }
    float idel = ih/iw;
    float th = (xc-icw)/iw;
    float t1m = th*(1.f-th);
    float den = idel + (d0+d1-2.f*idel)*t1m;
    float outv = ich + ih*(idel*th*th + d0*t1m)/den;
    float omt = 1.f-th;
    float dnum = idel*idel*(d1*th*th + 2.f*idel*t1m + d0*omt*omt);
    float lad = logf(dnum) - 2.f*logf(den);
    float y = inside ? outv : xs;
    lad = inside ? lad : 0.f;
    *z1p = y*m;
    *z0p = (*z0p)*m;
    ladm = lad*m;
    redS[tid] = ladm;
  }
  __syncthreads();
  if (tid == 0){
    float ssum = 0.f;
    #pragma unroll
    for (int i=0;i<32;i++) ssum += redS[i];
    atomicAdd(acco + b, -ssum);
  }
}

// ---------------- z init ----------------
__global__ __launch_bounds__(256) void init_z_k(
    const float* __restrict__ e_q, const float* __restrict__ mask,
    const float* __restrict__ pm, const float* __restrict__ pl,
    float* __restrict__ z, float* __restrict__ acc){
  __shared__ float red[256];
  int b = blockIdx.y; int t = blockIdx.x*256 + threadIdx.x;
  float m = mask[(size_t)b*TTT + t];
  float pl0=pl[0], pl1=pl[1];
  float e0 = e_q[((size_t)b*2+0)*TTT + t]*m;
  float e1 = e_q[((size_t)b*2+1)*TTT + t]*m;
  z[((size_t)b*2+0)*TTT + t] = fmaf(__expf(pl0), e0, pm[0])*m;
  z[((size_t)b*2+1)*TTT + t] = fmaf(__expf(pl1), e1, pm[1])*m;
  float contrib = -0.5f*(LOG2PI_F + e0*e0)*m - 0.5f*(LOG2PI_F + e1*e1)*m - (pl0+pl1)*m;
  int tid = threadIdx.x;
  red[tid] = contrib;
  __syncthreads();
  for (int o=128;o>0;o>>=1){ if (tid<o) red[tid]+=red[tid+o]; __syncthreads(); }
  if (tid==0) atomicAdd(acc+b, red[0]);
}

// ---------------- between p-flows and f-flows ----------------
__global__ __launch_bounds__(256) void final_pre_k(
    float* __restrict__ z, const float* __restrict__ w_in, const float* __restrict__ mask,
    const float* __restrict__ am, const float* __restrict__ al, float* __restrict__ acc){
  __shared__ float red[256];
  int b = blockIdx.y; int t = blockIdx.x*256 + threadIdx.x;
  float m = mask[(size_t)b*TTT + t];
  float zu  = z[((size_t)b*2+0)*TTT + t];
  float z1v = z[((size_t)b*2+1)*TTT + t];
  float wv  = w_in[(size_t)b*TTT + t];
  float u  = m / (1.f + __expf(-zu));
  float z0 = (wv - u)*m;
  float y0 = logf(fmaxf(z0, 1e-5f))*m;
  float al0=al[0], al1=al[1];
  z[((size_t)b*2+0)*TTT + t] = fmaf(__expf(al0), y0,  am[0])*m;
  z[((size_t)b*2+1)*TTT + t] = fmaf(__expf(al1), z1v, am[1])*m;
  float contrib = -(logsig_f(zu)+logsig_f(-zu))*m + y0 - (al0+al1)*m;
  int tid = threadIdx.x;
  red[tid] = contrib;
  __syncthreads();
  for (int o=128;o>0;o>>=1){ if (tid<o) red[tid]+=red[tid+o]; __syncthreads(); }
  if (tid==0) atomicAdd(acc+b, red[0]);
}

// ---------------- final 0.5(log2pi + z^2) sum ----------------
__global__ __launch_bounds__(256) void final_post_k(
    const float* __restrict__ z, const float* __restrict__ mask, float* __restrict__ acc){
  __shared__ float red[256];
  int b = blockIdx.y; int t = blockIdx.x*256 + threadIdx.x;
  float m = mask[(size_t)b*TTT + t];
  float z0 = z[((size_t)b*2+0)*TTT + t];
  float z1 = z[((size_t)b*2+1)*TTT + t];
  float contrib = 0.5f*(LOG2PI_F + z0*z0)*m + 0.5f*(LOG2PI_F + z1*z1)*m;
  int tid = threadIdx.x;
  red[tid] = contrib;
  __syncthreads();
  for (int o=128;o>0;o>>=1){ if (tid<o) red[tid]+=red[tid+o]; __syncthreads(); }
  if (tid==0) atomicAdd(acc+b, red[0]);
}

__global__ void write_out_k(const float* __restrict__ acc, float* __restrict__ out, int n){
  int i = threadIdx.x;
  if (i < n) out[i] = acc[i];
}

extern "C" void kernel_launch(void* const* d_in, const int* in_sizes, int n_in,
                              void* d_out, int out_size, void* d_ws, size_t ws_size,
                              hipStream_t stream){
  (void)n_in; (void)out_size; (void)ws_size;
  const float* x         = (const float*)d_in[0];
  const float* mask      = (const float*)d_in[1];
  const float* w_in      = (const float*)d_in[2];
  const float* e_q       = (const float*)d_in[3];
  const float* pre_w     = (const float*)d_in[4];
  const float* pre_b     = (const float*)d_in[5];
  const float* proj_w    = (const float*)d_in[6];
  const float* proj_b    = (const float*)d_in[7];
  const float* dds_dep_w = (const float*)d_in[8];
  const float* dds_dep_b = (const float*)d_in[9];
  const float* dds_pw_w  = (const float*)d_in[10];
  const float* dds_pw_b  = (const float*)d_in[11];
  const float* dds_ln_g  = (const float*)d_in[12];
  const float* dds_ln_b  = (const float*)d_in[13];
  const float* post_pre_w  = (const float*)d_in[14];
  const float* post_pre_b  = (const float*)d_in[15];
  const float* post_proj_w = (const float*)d_in[16];
  const float* post_proj_b = (const float*)d_in[17];
  const float* pdds_dep_w  = (const float*)d_in[18];
  const float* pdds_dep_b  = (const float*)d_in[19];
  const float* pdds_pw_w   = (const float*)d_in[20];
  const float* pdds_pw_b   = (const float*)d_in[21];
  const float* pdds_ln_g   = (const float*)d_in[22];
  const float* pdds_ln_b   = (const float*)d_in[23];
  const float* aff_m    = (const float*)d_in[24];
  const float* aff_logs = (const float*)d_in[25];
  const float* f_pre_w  = (const float*)d_in[26];
  const float* f_pre_b  = (const float*)d_in[27];
  const float* f_dep_w  = (const float*)d_in[28];
  const float* f_dep_b  = (const float*)d_in[29];
  const float* f_pw_w   = (const float*)d_in[30];
  const float* f_pw_b   = (const float*)d_in[31];
  const float* f_ln_g   = (const float*)d_in[32];
  const float* f_ln_b   = (const float*)d_in[33];
  const float* f_proj_w = (const float*)d_in[34];
  const float* f_proj_b = (const float*)d_in[35];
  const float* paff_m    = (const float*)d_in[36];
  const float* paff_logs = (const float*)d_in[37];
  const float* p_pre_w  = (const float*)d_in[38];
  const float* p_pre_b  = (const float*)d_in[39];
  const float* p_dep_w  = (const float*)d_in[40];
  const float* p_dep_b  = (const float*)d_in[41];
  const float* p_pw_w   = (const float*)d_in[42];
  const float* p_pw_b   = (const float*)d_in[43];
  const float* p_ln_g   = (const float*)d_in[44];
  const float* p_ln_b   = (const float*)d_in[45];
  const float* p_proj_w = (const float*)d_in[46];
  const float* p_proj_b = (const float*)d_in[47];

  int Bn = in_sizes[0] / (CC*TTT);
  size_t big = (size_t)Bn*CC*TTT;
  float* A    = (float*)d_ws;
  float* Bb   = A + big;
  float* H    = Bb + big;
  float* GP   = H + big;
  float* zbuf = GP + big;
  float* acc  = zbuf + (size_t)Bn*2*TTT;
  unsigned short* Wb = (unsigned short*)(acc + ((Bn + 3) & ~3));

  hipMemsetAsync(acc, 0, Bn*sizeof(float), stream);
  convert_w_k<<<(33*WSLOT + 255)/256, 256, 0, stream>>>(
      pre_w, proj_w, post_proj_w, dds_pw_w, pdds_pw_w, p_pw_w, f_pw_w, Wb);

  dim3 g32(TTT/32, Bn), g256(TTT/256, Bn);
  dim3 b256(256);

  unsigned short* W_pre      = Wb + 0*(size_t)WSLOT;
  unsigned short* W_proj     = Wb + 1*(size_t)WSLOT;
  unsigned short* W_postproj = Wb + 2*(size_t)WSLOT;
  unsigned short* W_dds      = Wb + 3*(size_t)WSLOT;
  unsigned short* W_pdds     = Wb + 6*(size_t)WSLOT;
  unsigned short* W_ppw      = Wb + 9*(size_t)WSLOT;
  unsigned short* W_fpw      = Wb + 21*(size_t)WSLOT;

  const int dils[3] = {1,3,9};

  // generic layer launcher
  auto layer = [&](const float* bin, float* bout,
                   const float* src1, int s1s, const float* pw1, const float* pb1,
                   const float* gptr, int srcmode, int outmode,
                   const float* dep_w, const float* dep_b, unsigned short* Ws,
                   const float* pw_b, const float* ln_g, const float* ln_b, int li,
                   const float* projW, const float* projB, float* zp, int zs){
    dds_fused_k<<<g32, b256, 0, stream>>>(
      bin, src1, s1s, pw1, pb1, gptr, bout, mask,
      dep_w + (size_t)li*CC*3, dep_b + (size_t)li*CC,
      ln_g + (size_t)(li*2+0)*CC, ln_b + (size_t)(li*2+0)*CC,
      Ws + (size_t)li*WSLOT, pw_b + (size_t)li*CC,
      ln_g + (size_t)(li*2+1)*CC, ln_b + (size_t)(li*2+1)*CC,
      dils[li], srcmode, outmode, projW, projB, zp, zs, acc);
  };

  // ---- h path ----
  conv_cc_k<<<g32, b256, 0, stream>>>(x, W_pre, pre_b, mask, nullptr, A, 0);
  layer(A, Bb, nullptr,0,nullptr,nullptr,nullptr, 0,0, dds_dep_w, dds_dep_b, W_dds, dds_pw_b, dds_ln_g, dds_ln_b, 0, nullptr,nullptr,nullptr,0);
  layer(Bb, A, nullptr,0,nullptr,nullptr,nullptr, 0,0, dds_dep_w, dds_dep_b, W_dds, dds_pw_b, dds_ln_g, dds_ln_b, 1, nullptr,nullptr,nullptr,0);
  layer(A, Bb, nullptr,0,nullptr,nullptr,nullptr, 0,0, dds_dep_w, dds_dep_b, W_dds, dds_pw_b, dds_ln_g, dds_ln_b, 2, nullptr,nullptr,nullptr,0);
  conv_cc_k<<<g32, b256, 0, stream>>>(Bb, W_proj, proj_b, mask, nullptr, H, 1);

  // ---- hw path (rank-1 pre fused into layer 0, g = null) ----
  layer(nullptr, A, w_in, TTT, post_pre_w, post_pre_b, nullptr, 1,0, pdds_dep_w, pdds_dep_b, W_pdds, pdds_pw_b, pdds_ln_g, pdds_ln_b, 0, nullptr,nullptr,nullptr,0);
  layer(A, Bb, nullptr,0,nullptr,nullptr,nullptr, 0,0, pdds_dep_w, pdds_dep_b, W_pdds, pdds_pw_b, pdds_ln_g, pdds_ln_b, 1, nullptr,nullptr,nullptr,0);
  layer(Bb, A, nullptr,0,nullptr,nullptr,nullptr, 0,0, pdds_dep_w, pdds_dep_b, W_pdds, pdds_pw_b, pdds_ln_g, pdds_ln_b, 2, nullptr,nullptr,nullptr,0);
  conv_cc_k<<<g32, b256, 0, stream>>>(A, W_postproj, post_proj_b, mask, H, GP, 2);

  // ---- init z ----
  init_z_k<<<g256, b256, 0, stream>>>(e_q, mask, paff_m, paff_logs, zbuf, acc);

  // ---- 4 posterior flows (g = GP) ----
  for (int f=0; f<4; f++){
    int s = f & 1;
    const float* dep_w = p_dep_w + (size_t)f*3*CC*3;
    const float* dep_b = p_dep_b + (size_t)f*3*CC;
    unsigned short* Ws = W_ppw + (size_t)f*3*WSLOT;
    const float* pw_b  = p_pw_b + (size_t)f*3*CC;
    const float* ln_g  = p_ln_g + (size_t)f*3*2*CC;
    const float* ln_b  = p_ln_b + (size_t)f*3*2*CC;
    layer(nullptr, A, zbuf + (size_t)s*TTT, 2*TTT, p_pre_w + (size_t)f*CC, p_pre_b + (size_t)f*CC, GP, 1,0, dep_w, dep_b, Ws, pw_b, ln_g, ln_b, 0, nullptr,nullptr,nullptr,0);
    layer(A, Bb, nullptr,0,nullptr,nullptr,nullptr, 0,0, dep_w, dep_b, Ws, pw_b, ln_g, ln_b, 1, nullptr,nullptr,nullptr,0);
    layer(Bb, nullptr, nullptr,0,nullptr,nullptr,nullptr, 0,1, dep_w, dep_b, Ws, pw_b, ln_g, ln_b, 2,
          p_proj_w + (size_t)f*PP*CC, p_proj_b + (size_t)f*PP, zbuf, s);
  }

  // ---- transition ----
  final_pre_k<<<g256, b256, 0, stream>>>(zbuf, w_in, mask, aff_m, aff_logs, acc);

  // ---- 4 flows (g = H) ----
  for (int f=0; f<4; f++){
    int s = f & 1;
    const float* dep_w = f_dep_w + (size_t)f*3*CC*3;
    const float* dep_b = f_dep_b + (size_t)f*3*CC;
    unsigned short* Ws = W_fpw + (size_t)f*3*WSLOT;
    const float* pw_b  = f_pw_b + (size_t)f*3*CC;
    const float* ln_g  = f_ln_g + (size_t)f*3*2*CC;
    const float* ln_b  = f_ln_b + (size_t)f*3*2*CC;
    layer(nullptr, A, zbuf + (size_t)s*TTT, 2*TTT, f_pre_w + (size_t)f*CC, f_pre_b + (size_t)f*CC, H, 1,0, dep_w, dep_b, Ws, pw_b, ln_g, ln_b, 0, nullptr,nullptr,nullptr,0);
    layer(A, Bb, nullptr,0,nullptr,nullptr,nullptr, 0,0, dep_w, dep_b, Ws, pw_b, ln_g, ln_b, 1, nullptr,nullptr,nullptr,0);
    layer(Bb, nullptr, nullptr,0,nullptr,nullptr,nullptr, 0,1, dep_w, dep_b, Ws, pw_b, ln_g, ln_b, 2,
          f_proj_w + (size_t)f*PP*CC, f_proj_b + (size_t)f*PP, zbuf, s);
  }

  final_post_k<<<g256, b256, 0, stream>>>(zbuf, mask, acc);
  write_out_k<<<1, 64, 0, stream>>>(acc, (float*)d_out, Bn);
}